// Round 5
// baseline (499.255 us; speedup 1.0000x reference)
//
#include <hip/hip_runtime.h>
#include <hip/hip_bf16.h>

typedef __bf16 bf16x8 __attribute__((ext_vector_type(8)));
typedef float f32x16 __attribute__((ext_vector_type(16)));

constexpr int NROW = 8192;
constexpr int DCOL = 256;
constexpr int BM = 256;                    // 256x256 output tile, 8 waves
constexpr int BK = 64;                     // 4 K-steps over D=256
constexpr int NT = NROW / BM;              // 32 tile-rows
constexpr int NTILES = NT * (NT + 1) / 2;  // 528 upper-tri tiles (528 % 8 == 0)
constexpr float MARGIN = 0.3f;

// async global->LDS, 16B per lane; LDS dest is wave-uniform base (HW adds lane*16)
__device__ inline void gload16(const unsigned short* g, unsigned short* l) {
    __builtin_amdgcn_global_load_lds(
        (const __attribute__((address_space(1))) void*)g,
        (__attribute__((address_space(3))) void*)l, 16, 0, 0);
}

// ---------------- normalize rows -> bf16, zero accumulator + counter ----------------
__global__ __launch_bounds__(256) void normalize_kernel(const float* __restrict__ hidden,
                                                        unsigned short* __restrict__ xn,
                                                        float* __restrict__ acc,
                                                        int* __restrict__ counter) {
    if (blockIdx.x == 0 && threadIdx.x == 0) { acc[0] = 0.0f; counter[0] = 0; }
    int wid = threadIdx.x >> 6, lane = threadIdx.x & 63;
    int row = (blockIdx.x << 2) + wid;           // 4 rows per block (one per wave)
    const float4* src = reinterpret_cast<const float4*>(hidden + (size_t)row * DCOL);
    float4 v = src[lane];
    float ss = v.x * v.x + v.y * v.y + v.z * v.z + v.w * v.w;
    #pragma unroll
    for (int off = 32; off; off >>= 1) ss += __shfl_down(ss, off);
    ss = __shfl(ss, 0);
    float inv = 1.0f / fmaxf(sqrtf(ss), 1e-8f);
    __hip_bfloat16 b0 = __float2bfloat16(v.x * inv);
    __hip_bfloat16 b1 = __float2bfloat16(v.y * inv);
    __hip_bfloat16 b2 = __float2bfloat16(v.z * inv);
    __hip_bfloat16 b3 = __float2bfloat16(v.w * inv);
    ushort4 o;
    o.x = *reinterpret_cast<unsigned short*>(&b0);
    o.y = *reinterpret_cast<unsigned short*>(&b1);
    o.z = *reinterpret_cast<unsigned short*>(&b2);
    o.w = *reinterpret_cast<unsigned short*>(&b3);
    reinterpret_cast<ushort4*>(xn + (size_t)row * DCOL)[lane] = o;
}

// ---------------- 256x256-tile MFMA Gram + fused pair loss + fused finalize ----------------
__global__ __launch_bounds__(512, 4) void pairloss_kernel(const unsigned short* __restrict__ xn,
                                                          const int* __restrict__ labels,
                                                          float* __restrict__ acc_out,
                                                          int* __restrict__ counter,
                                                          float* __restrict__ out) {
    __shared__ unsigned short As[BM * BK];   // 32KB, linear, XOR-swizzled contents
    __shared__ unsigned short Bs[BM * BK];   // 32KB
    __shared__ int lblA[BM], lblB[BM];
    __shared__ float wsum[8];

    // XCD-aware bijective swizzle: XCD x owns a contiguous tile range -> L2 reuse
    int bid = (int)(blockIdx.x & 7) * (NTILES / 8) + (int)(blockIdx.x >> 3);
    // unrank -> upper-triangular (bi, bj), bi <= bj
    int bi = 0, rem = bid;
    while (rem >= NT - bi) { rem -= NT - bi; ++bi; }   // uniform scalar loop, <=32 iters
    int bj = bi + rem;

    int tid = threadIdx.x;
    int wid = tid >> 6, lane = tid & 63;
    int wr = wid >> 2, wc = wid & 3;                   // 2x4 wave grid; wave tile 128x64
    int brow = bi * BM, bcol = bj * BM;

    if (tid < BM) lblA[tid] = labels[brow + tid];
    else          lblB[tid - BM] = labels[bcol + tid - BM];

    f32x16 acc[4][2] = {};                             // 4x2 tiles of 32x32 per wave

    // staging: one gload16 fills 8 rows x 128B; lane -> row rg+(lane>>3), slot lane&7
    int srow = lane >> 3;
    int schunk = (lane & 7) ^ srow;                    // pre-swizzled source chunk (r&7 == srow)
    const unsigned short* gA0 = xn + (size_t)brow * DCOL;
    const unsigned short* gB0 = xn + (size_t)bcol * DCOL;

    int lo = lane & 31, l7 = lane & 7, hi = lane >> 5;

    for (int ks = 0; ks < DCOL / BK; ++ks) {           // 4 K-steps
        __syncthreads();                               // previous step's readers done
        #pragma unroll
        for (int q = 0; q < 4; ++q) {
            int rg = (wid * 4 + q) * 8;                // wave-uniform 8-row group
            int goff = (rg + srow) * DCOL + ks * BK + schunk * 8;
            gload16(gA0 + goff, &As[rg * BK]);         // 8 rows x 128B, linear dest
            gload16(gB0 + goff, &Bs[rg * BK]);
        }
        __syncthreads();                               // compiler drains vmcnt before barrier
        #pragma unroll
        for (int kk = 0; kk < 4; ++kk) {               // K16 sub-steps of BK=64
            bf16x8 af[4], bfr[2];
            int cb = kk * 2 + hi;                      // 16B k-chunk 0..7
            #pragma unroll
            for (int m = 0; m < 4; ++m) {
                int r = wr * 128 + m * 32 + lo;        // r&7 == lane&7
                af[m] = *reinterpret_cast<const bf16x8*>(&As[r * BK + ((cb ^ l7) << 3)]);
            }
            #pragma unroll
            for (int n = 0; n < 2; ++n) {
                int r = wc * 64 + n * 32 + lo;
                bfr[n] = *reinterpret_cast<const bf16x8*>(&Bs[r * BK + ((cb ^ l7) << 3)]);
            }
            #pragma unroll
            for (int m = 0; m < 4; ++m)
                #pragma unroll
                for (int n = 0; n < 2; ++n)
                    acc[m][n] = __builtin_amdgcn_mfma_f32_32x32x16_bf16(af[m], bfr[n], acc[m][n], 0, 0, 0);
        }
    }

    // epilogue: per-pair loss, strict upper triangle
    // 32x32 C/D: col = lane&31, row = (reg&3) + 8*(reg>>2) + 4*(lane>>5)
    float local = 0.0f;
    #pragma unroll
    for (int m = 0; m < 4; ++m) {
        #pragma unroll
        for (int n = 0; n < 2; ++n) {
            #pragma unroll
            for (int g = 0; g < 16; ++g) {
                int crow = (g & 3) + 8 * (g >> 2) + 4 * hi;
                int il = wr * 128 + m * 32 + crow;
                int jl = wc * 64 + n * 32 + lo;
                int gi = brow + il, gj = bcol + jl;
                float sim = acc[m][n][g];
                float v = (lblA[il] == lblB[jl]) ? (1.0f - sim) : fmaxf(sim - MARGIN, 0.0f);
                local += (gi < gj) ? v : 0.0f;
            }
        }
    }
    #pragma unroll
    for (int off = 32; off; off >>= 1) local += __shfl_down(local, off);
    if (lane == 0) wsum[wid] = local;
    __syncthreads();
    if (tid == 0) {
        float bsum = 0.0f;
        #pragma unroll
        for (int w = 0; w < 8; ++w) bsum += wsum[w];
        atomicAdd(acc_out, bsum);                      // device-scope
        __threadfence();
        int c = atomicAdd(counter, 1);
        if (c == NTILES - 1) {                         // last block finalizes
            float total = atomicAdd(acc_out, 0.0f);    // returns full sum
            out[0] = total * (1.0f / 33550336.0f);     // / (N*(N-1)/2)
        }
    }
}

extern "C" void kernel_launch(void* const* d_in, const int* in_sizes, int n_in,
                              void* d_out, int out_size, void* d_ws, size_t ws_size,
                              hipStream_t stream) {
    const float* hidden = (const float*)d_in[0];
    const int* labels = (const int*)d_in[1];
    float* out = (float*)d_out;

    float* acc = (float*)d_ws;
    int* counter = (int*)((char*)d_ws + 4);
    unsigned short* xn = (unsigned short*)((char*)d_ws + 256);

    normalize_kernel<<<NROW / 4, 256, 0, stream>>>(hidden, xn, acc, counter);
    pairloss_kernel<<<NTILES, 512, 0, stream>>>(xn, labels, acc, counter, out);
}

// Round 6
// 46.981 us; speedup vs baseline: 10.6267x; 10.6267x over previous
//
#include <hip/hip_runtime.h>
#include <hip/hip_bf16.h>

typedef __bf16 bf16x8 __attribute__((ext_vector_type(8)));
typedef float f32x16 __attribute__((ext_vector_type(16)));

constexpr int NROW = 8192;
constexpr int DCOL = 256;
constexpr int BM = 256;                    // 256x256 output tile, 8 waves
constexpr int BK = 64;                     // 4 K-steps over D=256
constexpr int NT = NROW / BM;              // 32 tile-rows
constexpr int NTILES = NT * (NT + 1) / 2;  // 528 upper-tri tiles (528 % 8 == 0)
constexpr float MARGIN = 0.3f;

// async global->LDS, 16B per lane; LDS dest is wave-uniform base (HW adds lane*16)
__device__ inline void gload16(const unsigned short* g, unsigned short* l) {
    __builtin_amdgcn_global_load_lds(
        (const __attribute__((address_space(1))) void*)g,
        (__attribute__((address_space(3))) void*)l, 16, 0, 0);
}

// ---------------- normalize rows -> bf16 ----------------
__global__ __launch_bounds__(256) void normalize_kernel(const float* __restrict__ hidden,
                                                        unsigned short* __restrict__ xn) {
    int wid = threadIdx.x >> 6, lane = threadIdx.x & 63;
    int row = (blockIdx.x << 2) + wid;           // 4 rows per block (one per wave)
    const float4* src = reinterpret_cast<const float4*>(hidden + (size_t)row * DCOL);
    float4 v = src[lane];
    float ss = v.x * v.x + v.y * v.y + v.z * v.z + v.w * v.w;
    #pragma unroll
    for (int off = 32; off; off >>= 1) ss += __shfl_down(ss, off);
    ss = __shfl(ss, 0);
    float inv = 1.0f / fmaxf(sqrtf(ss), 1e-8f);
    __hip_bfloat16 b0 = __float2bfloat16(v.x * inv);
    __hip_bfloat16 b1 = __float2bfloat16(v.y * inv);
    __hip_bfloat16 b2 = __float2bfloat16(v.z * inv);
    __hip_bfloat16 b3 = __float2bfloat16(v.w * inv);
    ushort4 o;
    o.x = *reinterpret_cast<unsigned short*>(&b0);
    o.y = *reinterpret_cast<unsigned short*>(&b1);
    o.z = *reinterpret_cast<unsigned short*>(&b2);
    o.w = *reinterpret_cast<unsigned short*>(&b3);
    reinterpret_cast<ushort4*>(xn + (size_t)row * DCOL)[lane] = o;
}

// ---------------- 256x256-tile MFMA Gram + fused pair loss -> per-block partial ----------------
__global__ __launch_bounds__(512) void pairloss_kernel(const unsigned short* __restrict__ xn,
                                                       const int* __restrict__ labels,
                                                       float* __restrict__ partials) {
    __shared__ unsigned short As[BM * BK];   // 32KB, linear, XOR-swizzled contents
    __shared__ unsigned short Bs[BM * BK];   // 32KB
    __shared__ int lblA[BM], lblB[BM];
    __shared__ float wsum[8];

    // XCD-aware bijective swizzle: XCD x owns a contiguous tile range -> L2 reuse
    int bid = (int)(blockIdx.x & 7) * (NTILES / 8) + (int)(blockIdx.x >> 3);
    // unrank -> upper-triangular (bi, bj), bi <= bj
    int bi = 0, rem = bid;
    while (rem >= NT - bi) { rem -= NT - bi; ++bi; }   // uniform scalar loop, <=32 iters
    int bj = bi + rem;

    int tid = threadIdx.x;
    int wid = tid >> 6, lane = tid & 63;
    int wr = wid >> 2, wc = wid & 3;                   // 2x4 wave grid; wave tile 128x64
    int brow = bi * BM, bcol = bj * BM;

    if (tid < BM) lblA[tid] = labels[brow + tid];
    else          lblB[tid - BM] = labels[bcol + tid - BM];

    f32x16 acc[4][2] = {};                             // 4x2 tiles of 32x32 per wave

    // staging: one gload16 fills 8 rows x 128B; lane -> row rg+(lane>>3), slot lane&7
    int srow = lane >> 3;
    int schunk = (lane & 7) ^ srow;                    // pre-swizzled source chunk (r&7 == srow)
    const unsigned short* gA0 = xn + (size_t)brow * DCOL;
    const unsigned short* gB0 = xn + (size_t)bcol * DCOL;

    int lo = lane & 31, l7 = lane & 7, hi = lane >> 5;

    for (int ks = 0; ks < DCOL / BK; ++ks) {           // 4 K-steps
        __syncthreads();                               // previous step's readers done
        #pragma unroll
        for (int q = 0; q < 4; ++q) {
            int rg = (wid * 4 + q) * 8;                // wave-uniform 8-row group
            int goff = (rg + srow) * DCOL + ks * BK + schunk * 8;
            gload16(gA0 + goff, &As[rg * BK]);         // 8 rows x 128B, linear dest
            gload16(gB0 + goff, &Bs[rg * BK]);
        }
        __syncthreads();                               // compiler drains vmcnt before barrier
        #pragma unroll
        for (int kk = 0; kk < 4; ++kk) {               // K16 sub-steps of BK=64
            bf16x8 af[4], bfr[2];
            int cb = kk * 2 + hi;                      // 16B k-chunk 0..7
            #pragma unroll
            for (int m = 0; m < 4; ++m) {
                int r = wr * 128 + m * 32 + lo;        // r&7 == lane&7
                af[m] = *reinterpret_cast<const bf16x8*>(&As[r * BK + ((cb ^ l7) << 3)]);
            }
            #pragma unroll
            for (int n = 0; n < 2; ++n) {
                int r = wc * 64 + n * 32 + lo;
                bfr[n] = *reinterpret_cast<const bf16x8*>(&Bs[r * BK + ((cb ^ l7) << 3)]);
            }
            #pragma unroll
            for (int m = 0; m < 4; ++m)
                #pragma unroll
                for (int n = 0; n < 2; ++n)
                    acc[m][n] = __builtin_amdgcn_mfma_f32_32x32x16_bf16(af[m], bfr[n], acc[m][n], 0, 0, 0);
        }
    }

    // epilogue: per-pair loss, strict upper triangle
    // 32x32 C/D: col = lane&31, row = (reg&3) + 8*(reg>>2) + 4*(lane>>5)
    float local = 0.0f;
    #pragma unroll
    for (int m = 0; m < 4; ++m) {
        #pragma unroll
        for (int n = 0; n < 2; ++n) {
            #pragma unroll
            for (int g = 0; g < 16; ++g) {
                int crow = (g & 3) + 8 * (g >> 2) + 4 * hi;
                int il = wr * 128 + m * 32 + crow;
                int jl = wc * 64 + n * 32 + lo;
                int gi = brow + il, gj = bcol + jl;
                float sim = acc[m][n][g];
                float v = (lblA[il] == lblB[jl]) ? (1.0f - sim) : fmaxf(sim - MARGIN, 0.0f);
                local += (gi < gj) ? v : 0.0f;
            }
        }
    }
    #pragma unroll
    for (int off = 32; off; off >>= 1) local += __shfl_down(local, off);
    if (lane == 0) wsum[wid] = local;
    __syncthreads();
    if (tid == 0) {
        float bsum = 0.0f;
        #pragma unroll
        for (int w = 0; w < 8; ++w) bsum += wsum[w];
        partials[blockIdx.x] = bsum;                   // distinct address per block, no atomics
    }
}

// ---------------- reduce 528 partials -> loss ----------------
__global__ __launch_bounds__(512) void finalize_kernel(const float* __restrict__ partials,
                                                       float* __restrict__ out) {
    __shared__ float wsum[8];
    int tid = threadIdx.x, wid = tid >> 6, lane = tid & 63;
    float s = (tid < NTILES) ? partials[tid] : 0.0f;
    if (tid + 512 < NTILES) s += partials[tid + 512];
    #pragma unroll
    for (int off = 32; off; off >>= 1) s += __shfl_down(s, off);
    if (lane == 0) wsum[wid] = s;
    __syncthreads();
    if (tid == 0) {
        float total = 0.0f;
        #pragma unroll
        for (int w = 0; w < 8; ++w) total += wsum[w];
        out[0] = total * (1.0f / 33550336.0f);         // / (N*(N-1)/2)
    }
}

extern "C" void kernel_launch(void* const* d_in, const int* in_sizes, int n_in,
                              void* d_out, int out_size, void* d_ws, size_t ws_size,
                              hipStream_t stream) {
    const float* hidden = (const float*)d_in[0];
    const int* labels = (const int*)d_in[1];
    float* out = (float*)d_out;

    unsigned short* xn = (unsigned short*)d_ws;                            // 4 MB
    float* partials = (float*)((char*)d_ws + (size_t)NROW * DCOL * 2);     // 528 floats

    normalize_kernel<<<NROW / 4, 256, 0, stream>>>(hidden, xn);
    pairloss_kernel<<<NTILES, 512, 0, stream>>>(xn, labels, partials);
    finalize_kernel<<<1, 512, 0, stream>>>(partials, out);
}

// Round 7
// 45.929 us; speedup vs baseline: 10.8701x; 1.0229x over previous
//
#include <hip/hip_runtime.h>
#include <hip/hip_bf16.h>

typedef __bf16 bf16x8 __attribute__((ext_vector_type(8)));
typedef float f32x16 __attribute__((ext_vector_type(16)));

constexpr int NROW = 8192;
constexpr int DCOL = 256;
constexpr int BM = 256;                    // 256x256 output tile, 8 waves
constexpr int BK = 64;                     // 4 K-tiles over D=256
constexpr int NKT = DCOL / BK;             // 4
constexpr int NT = NROW / BM;              // 32 tile-rows
constexpr int NTILES = NT * (NT + 1) / 2;  // 528 upper-tri tiles (528 % 8 == 0)
constexpr float MARGIN = 0.3f;

// async global->LDS, 16B per lane; LDS dest is wave-uniform base (HW adds lane*16)
__device__ inline void gload16(const unsigned short* g, unsigned short* l) {
    __builtin_amdgcn_global_load_lds(
        (const __attribute__((address_space(1))) void*)g,
        (__attribute__((address_space(3))) void*)l, 16, 0, 0);
}

// ---------------- normalize rows -> bf16 ----------------
__global__ __launch_bounds__(256) void normalize_kernel(const float* __restrict__ hidden,
                                                        unsigned short* __restrict__ xn) {
    int wid = threadIdx.x >> 6, lane = threadIdx.x & 63;
    int row = (blockIdx.x << 2) + wid;           // 4 rows per block (one per wave)
    const float4* src = reinterpret_cast<const float4*>(hidden + (size_t)row * DCOL);
    float4 v = src[lane];
    float ss = v.x * v.x + v.y * v.y + v.z * v.z + v.w * v.w;
    #pragma unroll
    for (int off = 32; off; off >>= 1) ss += __shfl_down(ss, off);
    ss = __shfl(ss, 0);
    float inv = 1.0f / fmaxf(sqrtf(ss), 1e-8f);
    __hip_bfloat16 b0 = __float2bfloat16(v.x * inv);
    __hip_bfloat16 b1 = __float2bfloat16(v.y * inv);
    __hip_bfloat16 b2 = __float2bfloat16(v.z * inv);
    __hip_bfloat16 b3 = __float2bfloat16(v.w * inv);
    ushort4 o;
    o.x = *reinterpret_cast<unsigned short*>(&b0);
    o.y = *reinterpret_cast<unsigned short*>(&b1);
    o.z = *reinterpret_cast<unsigned short*>(&b2);
    o.w = *reinterpret_cast<unsigned short*>(&b3);
    reinterpret_cast<ushort4*>(xn + (size_t)row * DCOL)[lane] = o;
}

// ---------------- 256x256-tile dbuf-prefetch MFMA Gram + fused pair loss ----------------
__global__ __launch_bounds__(512) void pairloss_kernel(const unsigned short* __restrict__ xn,
                                                       const int* __restrict__ labels,
                                                       float* __restrict__ partials) {
    __shared__ unsigned short As[2][BM * BK];   // 2 x 32KB, linear, XOR-swizzled contents
    __shared__ unsigned short Bs[2][BM * BK];   // 2 x 32KB
    __shared__ int lblA[BM], lblB[BM];
    __shared__ float wsum[8];

    // XCD-aware bijective swizzle: XCD x owns a contiguous tile range -> L2 reuse
    int bid = (int)(blockIdx.x & 7) * (NTILES / 8) + (int)(blockIdx.x >> 3);
    // unrank -> upper-triangular (bi, bj), bi <= bj
    int bi = 0, rem = bid;
    while (rem >= NT - bi) { rem -= NT - bi; ++bi; }   // uniform scalar loop, <=32 iters
    int bj = bi + rem;

    int tid = threadIdx.x;
    int wid = tid >> 6, lane = tid & 63;
    int wr = wid >> 2, wc = wid & 3;                   // 2x4 wave grid; wave tile 128x64
    int brow = bi * BM, bcol = bj * BM;

    if (tid < BM) lblA[tid] = labels[brow + tid];
    else          lblB[tid - BM] = labels[bcol + tid - BM];

    f32x16 acc[4][2] = {};                             // 4x2 tiles of 32x32 per wave

    // staging: one gload16 fills 8 rows x 128B; lane -> row rg+(lane>>3), slot lane&7
    int srow = lane >> 3;
    int schunk = (lane & 7) ^ srow;                    // pre-swizzled source chunk (r&7 == srow)
    const unsigned short* gA0 = xn + (size_t)brow * DCOL;
    const unsigned short* gB0 = xn + (size_t)bcol * DCOL;

    int lo = lane & 31, l7 = lane & 7, hi = lane >> 5;

    // prologue: issue K-tile 0 into buffer 0
    #pragma unroll
    for (int q = 0; q < 4; ++q) {
        int rg = (wid * 4 + q) * 8;                    // wave-uniform 8-row group
        int goff = (rg + srow) * DCOL + 0 * BK + schunk * 8;
        gload16(gA0 + goff, &As[0][rg * BK]);
        gload16(gB0 + goff, &Bs[0][rg * BK]);
    }

    #pragma unroll
    for (int t = 0; t < NKT; ++t) {
        int c = t & 1;
        // tile t's loads were issued one full tile ago (except t=0) -> wait is ~free
        asm volatile("s_waitcnt vmcnt(0)" ::: "memory");
        __builtin_amdgcn_s_barrier();                  // all waves' tile-t data valid;
                                                       // also: buf[c^1] readers (tile t-1) done
        if (t + 1 < NKT) {                             // prefetch tile t+1 into buf[c^1]
            #pragma unroll
            for (int q = 0; q < 4; ++q) {
                int rg = (wid * 4 + q) * 8;
                int goff = (rg + srow) * DCOL + (t + 1) * BK + schunk * 8;
                gload16(gA0 + goff, &As[c ^ 1][rg * BK]);
                gload16(gB0 + goff, &Bs[c ^ 1][rg * BK]);
            }
        }
        #pragma unroll
        for (int kk = 0; kk < 4; ++kk) {               // K16 sub-steps of BK=64
            bf16x8 af[4], bfr[2];
            int cb = kk * 2 + hi;                      // 16B k-chunk 0..7
            #pragma unroll
            for (int m = 0; m < 4; ++m) {
                int r = wr * 128 + m * 32 + lo;        // r&7 == lane&7
                af[m] = *reinterpret_cast<const bf16x8*>(&As[c][r * BK + ((cb ^ l7) << 3)]);
            }
            #pragma unroll
            for (int n = 0; n < 2; ++n) {
                int r = wc * 64 + n * 32 + lo;
                bfr[n] = *reinterpret_cast<const bf16x8*>(&Bs[c][r * BK + ((cb ^ l7) << 3)]);
            }
            __builtin_amdgcn_s_setprio(1);
            #pragma unroll
            for (int m = 0; m < 4; ++m)
                #pragma unroll
                for (int n = 0; n < 2; ++n)
                    acc[m][n] = __builtin_amdgcn_mfma_f32_32x32x16_bf16(af[m], bfr[n], acc[m][n], 0, 0, 0);
            __builtin_amdgcn_s_setprio(0);
        }
    }

    // epilogue: per-pair loss, strict upper triangle
    // 32x32 C/D: col = lane&31, row = (reg&3) + 8*(reg>>2) + 4*(lane>>5)
    float local = 0.0f;
    #pragma unroll
    for (int m = 0; m < 4; ++m) {
        #pragma unroll
        for (int n = 0; n < 2; ++n) {
            #pragma unroll
            for (int g = 0; g < 16; ++g) {
                int crow = (g & 3) + 8 * (g >> 2) + 4 * hi;
                int il = wr * 128 + m * 32 + crow;
                int jl = wc * 64 + n * 32 + lo;
                int gi = brow + il, gj = bcol + jl;
                float sim = acc[m][n][g];
                float v = (lblA[il] == lblB[jl]) ? (1.0f - sim) : fmaxf(sim - MARGIN, 0.0f);
                local += (gi < gj) ? v : 0.0f;
            }
        }
    }
    #pragma unroll
    for (int off = 32; off; off >>= 1) local += __shfl_down(local, off);
    if (lane == 0) wsum[wid] = local;
    __syncthreads();
    if (tid == 0) {
        float bsum = 0.0f;
        #pragma unroll
        for (int w = 0; w < 8; ++w) bsum += wsum[w];
        partials[blockIdx.x] = bsum;                   // distinct address per block, no atomics
    }
}

// ---------------- reduce 528 partials -> loss ----------------
__global__ __launch_bounds__(512) void finalize_kernel(const float* __restrict__ partials,
                                                       float* __restrict__ out) {
    __shared__ float wsum[8];
    int tid = threadIdx.x, wid = tid >> 6, lane = tid & 63;
    float s = (tid < NTILES) ? partials[tid] : 0.0f;
    if (tid + 512 < NTILES) s += partials[tid + 512];
    #pragma unroll
    for (int off = 32; off; off >>= 1) s += __shfl_down(s, off);
    if (lane == 0) wsum[wid] = s;
    __syncthreads();
    if (tid == 0) {
        float total = 0.0f;
        #pragma unroll
        for (int w = 0; w < 8; ++w) total += wsum[w];
        out[0] = total * (1.0f / 33550336.0f);         // / (N*(N-1)/2)
    }
}

extern "C" void kernel_launch(void* const* d_in, const int* in_sizes, int n_in,
                              void* d_out, int out_size, void* d_ws, size_t ws_size,
                              hipStream_t stream) {
    const float* hidden = (const float*)d_in[0];
    const int* labels = (const int*)d_in[1];
    float* out = (float*)d_out;

    unsigned short* xn = (unsigned short*)d_ws;                            // 4 MB
    float* partials = (float*)((char*)d_ws + (size_t)NROW * DCOL * 2);     // 528 floats

    normalize_kernel<<<NROW / 4, 256, 0, stream>>>(hidden, xn);
    pairloss_kernel<<<NTILES, 512, 0, stream>>>(xn, labels, partials);
    finalize_kernel<<<1, 512, 0, stream>>>(partials, out);
}